// Round 3
// baseline (488.123 us; speedup 1.0000x reference)
//
#include <hip/hip_runtime.h>

#define NB 2
#define NH 16
#define SEQ 2048
#define DMODEL 1024
#define DHEAD 64
// 0.125 (1/sqrt(DH)) / ln(2): folded into Wq so softmax is a bare exp2
#define QSCALE 0.18033688f

typedef __attribute__((ext_vector_type(8))) short bf16x8;
typedef __attribute__((ext_vector_type(4))) float f32x4;

static __device__ __forceinline__ unsigned short f2bf(float f) {
    unsigned int u = __float_as_uint(f);
    u += 0x7fffu + ((u >> 16) & 1u);   // RNE
    return (unsigned short)(u >> 16);
}
static __device__ __forceinline__ unsigned int pk2(float lo, float hi) {
    return (unsigned int)f2bf(lo) | ((unsigned int)f2bf(hi) << 16);
}
static __device__ __forceinline__ void gld_lds16(const unsigned short* g, unsigned short* l) {
    __builtin_amdgcn_global_load_lds(
        (const __attribute__((address_space(1))) unsigned int*)g,
        (__attribute__((address_space(3))) unsigned int*)l, 16, 0, 0);
}

// =====================================================================
// Prep A: pack bool mask (int32) into u64 bitmask words per (b,s) row.
// =====================================================================
__global__ __launch_bounds__(256) void pack_mask_kernel(
    const int* __restrict__ mask, unsigned long long* __restrict__ mpack)
{
    const int wave = blockIdx.x * 4 + (threadIdx.x >> 6);
    const int lane = threadIdx.x & 63;
    const int* row = mask + (size_t)wave * SEQ;
    unsigned long long* orow = mpack + (size_t)wave * (SEQ / 64);
    for (int w = 0; w < SEQ / 64; ++w) {
        int m = row[w * 64 + lane];
        unsigned long long bits = __ballot(m != 0);
        if (lane == 0) orow[w] = bits;
    }
}

// =====================================================================
// Prep B1: fused Wq/Wk/Wv transpose+cvt (per head 1024x64 -> 64x1024).
// Wq additionally scaled by QSCALE. grid (16, 48).
// =====================================================================
__global__ __launch_bounds__(256) void transpose_qkv_kernel(
    const float* __restrict__ Wq, const float* __restrict__ Wk, const float* __restrict__ Wv,
    unsigned short* __restrict__ Wqt, unsigned short* __restrict__ Wkt, unsigned short* __restrict__ Wvt)
{
    const int z = blockIdx.y, sel = z >> 4, h = z & 15;
    const float* S = (sel == 0 ? Wq : sel == 1 ? Wk : Wv) + (size_t)h * DMODEL * DHEAD;
    unsigned short* D = (sel == 0 ? Wqt : sel == 1 ? Wkt : Wvt) + (size_t)h * DMODEL * DHEAD;
    const float scale = (sel == 0) ? QSCALE : 1.0f;
    const int tile_r = blockIdx.x * 64;
    __shared__ float Ls[64][65];
    const int t = threadIdx.x;
    const int c4 = (t & 15) * 4;
    for (int rr = t >> 4; rr < 64; rr += 16) {
        float4 v = *(const float4*)(S + (size_t)(tile_r + rr) * DHEAD + c4);
        Ls[rr][c4 + 0] = v.x; Ls[rr][c4 + 1] = v.y;
        Ls[rr][c4 + 2] = v.z; Ls[rr][c4 + 3] = v.w;
    }
    __syncthreads();
    const int r4 = (t & 15) * 4;
    for (int cc = t >> 4; cc < 64; cc += 16) {
        ushort4 o;
        o.x = f2bf(Ls[r4 + 0][cc] * scale); o.y = f2bf(Ls[r4 + 1][cc] * scale);
        o.z = f2bf(Ls[r4 + 2][cc] * scale); o.w = f2bf(Ls[r4 + 3][cc] * scale);
        *(ushort4*)(D + (size_t)cc * DMODEL + tile_r + r4) = o;
    }
}

// =====================================================================
// Prep B2: Wo transpose+cvt (1024x1024). grid (16, 16).
// =====================================================================
__global__ __launch_bounds__(256) void transpose_wo_kernel(
    const float* __restrict__ src, unsigned short* __restrict__ dst)
{
    const int tile_c = blockIdx.x * 64, tile_r = blockIdx.y * 64;
    __shared__ float Ls[64][65];
    const int t = threadIdx.x;
    const int c4 = (t & 15) * 4;
    for (int rr = t >> 4; rr < 64; rr += 16) {
        float4 v = *(const float4*)(src + (size_t)(tile_r + rr) * DMODEL + tile_c + c4);
        Ls[rr][c4 + 0] = v.x; Ls[rr][c4 + 1] = v.y;
        Ls[rr][c4 + 2] = v.z; Ls[rr][c4 + 3] = v.w;
    }
    __syncthreads();
    const int r4 = (t & 15) * 4;
    for (int cc = t >> 4; cc < 64; cc += 16) {
        ushort4 o;
        o.x = f2bf(Ls[r4 + 0][cc]); o.y = f2bf(Ls[r4 + 1][cc]);
        o.z = f2bf(Ls[r4 + 2][cc]); o.w = f2bf(Ls[r4 + 3][cc]);
        *(ushort4*)(dst + (size_t)(tile_c + cc) * DMODEL + tile_r + r4) = o;
    }
}

// =====================================================================
// Fused projection GEMM: z in {0,1,2} selects (q,Wqt->qh),(k,Wkt->kh),
// (v,Wvt->vt transposed [bh][dh][seq]).  128x128 tile, BK=64, 4 waves.
// grid (8, 32, 3) = 768 blocks (3 blocks/CU).
// =====================================================================
__global__ __launch_bounds__(256) void proj_gemm_kernel(
    const float* __restrict__ q, const float* __restrict__ k, const float* __restrict__ v,
    const unsigned short* __restrict__ Wqt, const unsigned short* __restrict__ Wkt,
    const unsigned short* __restrict__ Wvt,
    unsigned short* __restrict__ qh, unsigned short* __restrict__ kh,
    unsigned short* __restrict__ vt)
{
    const int z = blockIdx.z;
    const float* A = (z == 0) ? q : (z == 1) ? k : v;
    const unsigned short* Bt = (z == 0) ? Wqt : (z == 1) ? Wkt : Wvt;

    const int t = threadIdx.x, lane = t & 63, w = t >> 6;
    const int lg = lane >> 4, ln = lane & 15;
    const int wx = w & 1, wy = w >> 1;
    const int m0 = blockIdx.y * 128, n0 = blockIdx.x * 128;

    __shared__ __align__(16) unsigned short As[128 * 64];
    __shared__ __align__(16) unsigned short Bs[128 * 64];

    f32x4 acc[4][4] = {};

    for (int kk = 0; kk < DMODEL; kk += 64) {
        #pragma unroll
        for (int i = 0; i < 4; ++i) {
            int s = (w * 4 + i) * 64 + lane;
            int n = s >> 3, c = (s & 7) ^ (n & 7);
            gld_lds16(Bt + (size_t)(n0 + n) * DMODEL + kk + c * 8, Bs + (size_t)s * 8);
        }
        {
            const int row = t >> 1, kh2 = (t & 1) * 32;
            const float* Ag = A + (size_t)(m0 + row) * DMODEL + kk + kh2;
            #pragma unroll
            for (int j = 0; j < 4; ++j) {
                float4 x0 = *(const float4*)(Ag + j * 8);
                float4 x1 = *(const float4*)(Ag + j * 8 + 4);
                uint4 val;
                val.x = pk2(x0.x, x0.y); val.y = pk2(x0.z, x0.w);
                val.z = pk2(x1.x, x1.y); val.w = pk2(x1.z, x1.w);
                int c = (kh2 >> 3) + j;
                *(uint4*)(As + row * 64 + ((c ^ (row & 7)) * 8)) = val;
            }
        }
        __syncthreads();
        #pragma unroll
        for (int ks = 0; ks < 2; ++ks) {
            bf16x8 af[4], bf[4];
            #pragma unroll
            for (int rb = 0; rb < 4; ++rb) {
                int r = wy * 64 + rb * 16 + ln;
                af[rb] = *(const bf16x8*)(As + r * 64 + (((ks * 4 + lg) ^ (r & 7)) * 8));
            }
            #pragma unroll
            for (int nb = 0; nb < 4; ++nb) {
                int n = wx * 64 + nb * 16 + ln;
                bf[nb] = *(const bf16x8*)(Bs + n * 64 + (((ks * 4 + lg) ^ (n & 7)) * 8));
            }
            #pragma unroll
            for (int rb = 0; rb < 4; ++rb)
                #pragma unroll
                for (int nb = 0; nb < 4; ++nb)
                    acc[rb][nb] = __builtin_amdgcn_mfma_f32_16x16x32_bf16(
                        af[rb], bf[nb], acc[rb][nb], 0, 0, 0);
        }
        __syncthreads();
    }

    if (z < 2) {
        unsigned short* Y = (z == 0) ? qh : kh;   // [bh][s][dh]
        #pragma unroll
        for (int rb = 0; rb < 4; ++rb)
            #pragma unroll
            for (int nb = 0; nb < 4; ++nb)
                #pragma unroll
                for (int r = 0; r < 4; ++r) {
                    int grow = m0 + wy * 64 + rb * 16 + lg * 4 + r;   // b*2048+s
                    int gcol = n0 + wx * 64 + nb * 16 + ln;           // h*64+e
                    size_t idx = ((size_t)((grow >> 11) * NH + (gcol >> 6)) * SEQ
                                  + (grow & (SEQ - 1))) * DHEAD + (gcol & 63);
                    Y[idx] = f2bf(acc[rb][nb][r]);
                }
    } else {
        // V transposed: vt[bh][dh][seq]; 4 consecutive s per lane -> ushort4
        #pragma unroll
        for (int rb = 0; rb < 4; ++rb)
            #pragma unroll
            for (int nb = 0; nb < 4; ++nb) {
                int grow0 = m0 + wy * 64 + rb * 16 + lg * 4;          // b*2048+s (s%4==0)
                int gcol  = n0 + wx * 64 + nb * 16 + ln;              // h*64+dh
                int bh = ((grow0 >> 11) << 4) + (gcol >> 6);
                ushort4 st;
                st.x = f2bf(acc[rb][nb][0]); st.y = f2bf(acc[rb][nb][1]);
                st.z = f2bf(acc[rb][nb][2]); st.w = f2bf(acc[rb][nb][3]);
                *(ushort4*)(vt + ((size_t)bh * DHEAD + (gcol & 63)) * SEQ
                                 + (grow0 & (SEQ - 1))) = st;
            }
    }
}

// =====================================================================
// MFMA flash attention, barrier-free. grid (32, 32), block 256 (4 waves).
// Wave w owns q-rows [row0+16w, +16). No running max (logits bounded),
// l-reduction deferred to epilogue. K/V frags direct from global
// (V pre-transposed). Only LDS: wave-private P round-trip.
// =====================================================================
__global__ __launch_bounds__(256) void attn_kernel(
    const unsigned short* __restrict__ qh, const unsigned short* __restrict__ kh,
    const unsigned short* __restrict__ vt, const unsigned long long* __restrict__ mpack,
    unsigned short* __restrict__ att)
{
    const int t = threadIdx.x, lane = t & 63, w = t >> 6;
    const int lg = lane >> 4, ln = lane & 15;
    const int row0 = blockIdx.x * 64;
    const int bh = blockIdx.y, b = bh >> 4, h = bh & 15;

    __shared__ __align__(16) unsigned short Ps[4][16][72];  // wave-private P

    const unsigned short* Qb = qh + ((size_t)bh * SEQ + row0 + w * 16 + ln) * DHEAD;
    bf16x8 qf0 = *(const bf16x8*)(Qb + lg * 8);
    bf16x8 qf1 = *(const bf16x8*)(Qb + 32 + lg * 8);

    const unsigned short* Kb = kh + (size_t)bh * SEQ * DHEAD;
    const unsigned short* Vb = vt + (size_t)bh * DHEAD * SEQ;
    const unsigned long long* Mb = mpack + ((size_t)b * SEQ + row0 + w * 16) * (SEQ / 64);

    f32x4 O[4] = {};
    float lsum[4] = {0.f, 0.f, 0.f, 0.f};

    for (int kt = 0; kt < SEQ; kt += 64) {
        unsigned long long mw[4];
        #pragma unroll
        for (int r = 0; r < 4; ++r)
            mw[r] = Mb[(size_t)(lg * 4 + r) * (SEQ / 64) + (kt >> 6)];

        // ---- S = Q K^T (K B-frags direct from global) ----
        f32x4 S[4] = {};
        #pragma unroll
        for (int kb = 0; kb < 4; ++kb) {
            const unsigned short* kp = Kb + (size_t)(kt + kb * 16 + ln) * DHEAD + lg * 8;
            bf16x8 k0 = *(const bf16x8*)(kp);
            bf16x8 k1 = *(const bf16x8*)(kp + 32);
            S[kb] = __builtin_amdgcn_mfma_f32_16x16x32_bf16(qf0, k0, S[kb], 0, 0, 0);
            S[kb] = __builtin_amdgcn_mfma_f32_16x16x32_bf16(qf1, k1, S[kb], 0, 0, 0);
        }

        // ---- softmax numerator: p = masked ? 0 : exp2(s) ----
        #pragma unroll
        for (int r = 0; r < 4; ++r) {
            #pragma unroll
            for (int kb = 0; kb < 4; ++kb) {
                const bool m = (mw[r] >> (kb * 16 + ln)) & 1ull;
                float e = m ? 0.0f : exp2f(S[kb][r]);
                lsum[r] += e;
                Ps[w][lg * 4 + r][kb * 16 + ln] = f2bf(e);
            }
        }

        // ---- P A-frags (same-wave DS ordering; no barrier) ----
        const unsigned short* pb = &Ps[w][ln][lg * 8];
        bf16x8 af0 = *(const bf16x8*)(pb);
        bf16x8 af1 = *(const bf16x8*)(pb + 32);

        // ---- O += P @ V (V^T B-frags direct from global) ----
        #pragma unroll
        for (int nb = 0; nb < 4; ++nb) {
            const unsigned short* vp = Vb + (size_t)(nb * 16 + ln) * SEQ + kt + lg * 8;
            bf16x8 b0 = *(const bf16x8*)(vp);
            bf16x8 b1 = *(const bf16x8*)(vp + 32);
            O[nb] = __builtin_amdgcn_mfma_f32_16x16x32_bf16(af0, b0, O[nb], 0, 0, 0);
            O[nb] = __builtin_amdgcn_mfma_f32_16x16x32_bf16(af1, b1, O[nb], 0, 0, 0);
        }
    }

    // ---- epilogue: one l-reduction, normalize, head-concat store ----
    unsigned short* ob = att + ((size_t)b * SEQ + row0 + w * 16) * DMODEL + h * DHEAD;
    #pragma unroll
    for (int r = 0; r < 4; ++r) {
        float l = lsum[r];
        l += __shfl_xor(l, 1, 64);
        l += __shfl_xor(l, 2, 64);
        l += __shfl_xor(l, 4, 64);
        l += __shfl_xor(l, 8, 64);
        const float inv = 1.0f / l;
        #pragma unroll
        for (int nb = 0; nb < 4; ++nb)
            ob[(size_t)(lg * 4 + r) * DMODEL + nb * 16 + ln] = f2bf(O[nb][r] * inv);
    }
}

// =====================================================================
// Output GEMM: out[4096 x 1024] = att(bf16) @ Wot^T, f32 out.
// 128M x 64N tile, BK=64, 4 waves stacked in M. grid (16, 32) = 512 blocks.
// =====================================================================
__global__ __launch_bounds__(256) void out_gemm_kernel(
    const unsigned short* __restrict__ A, const unsigned short* __restrict__ Bt,
    float* __restrict__ C)
{
    const int t = threadIdx.x, lane = t & 63, w = t >> 6;
    const int lg = lane >> 4, ln = lane & 15;
    const int n0 = blockIdx.x * 64, m0 = blockIdx.y * 128;

    __shared__ __align__(16) unsigned short As[128 * 64];
    __shared__ __align__(16) unsigned short Bs[64 * 64];

    f32x4 acc[2][4] = {};

    for (int kk = 0; kk < DMODEL; kk += 64) {
        #pragma unroll
        for (int i = 0; i < 2; ++i) {
            int s = i * 256 + t;
            int n = s >> 3, c = (s & 7) ^ (n & 7);
            gld_lds16(Bt + (size_t)(n0 + n) * DMODEL + kk + c * 8, Bs + (size_t)s * 8);
        }
        #pragma unroll
        for (int i = 0; i < 4; ++i) {
            int s = i * 256 + t;
            int n = s >> 3, c = (s & 7) ^ (n & 7);
            gld_lds16(A + (size_t)(m0 + n) * DMODEL + kk + c * 8, As + (size_t)s * 8);
        }
        __syncthreads();
        #pragma unroll
        for (int ks = 0; ks < 2; ++ks) {
            bf16x8 af[2], bf[4];
            #pragma unroll
            for (int rb = 0; rb < 2; ++rb) {
                int r = w * 32 + rb * 16 + ln;
                af[rb] = *(const bf16x8*)(As + r * 64 + (((ks * 4 + lg) ^ (r & 7)) * 8));
            }
            #pragma unroll
            for (int nb = 0; nb < 4; ++nb) {
                int n = nb * 16 + ln;
                bf[nb] = *(const bf16x8*)(Bs + n * 64 + (((ks * 4 + lg) ^ (n & 7)) * 8));
            }
            #pragma unroll
            for (int rb = 0; rb < 2; ++rb)
                #pragma unroll
                for (int nb = 0; nb < 4; ++nb)
                    acc[rb][nb] = __builtin_amdgcn_mfma_f32_16x16x32_bf16(
                        af[rb], bf[nb], acc[rb][nb], 0, 0, 0);
        }
        __syncthreads();
    }

    #pragma unroll
    for (int rb = 0; rb < 2; ++rb)
        #pragma unroll
        for (int nb = 0; nb < 4; ++nb)
            #pragma unroll
            for (int r = 0; r < 4; ++r) {
                int grow = m0 + w * 32 + rb * 16 + lg * 4 + r;
                int gcol = n0 + nb * 16 + ln;
                C[(size_t)grow * DMODEL + gcol] = acc[rb][nb][r];
            }
}

extern "C" void kernel_launch(void* const* d_in, const int* in_sizes, int n_in,
                              void* d_out, int out_size, void* d_ws, size_t ws_size,
                              hipStream_t stream) {
    const float* q    = (const float*)d_in[0];
    const float* k    = (const float*)d_in[1];
    const float* v    = (const float*)d_in[2];
    const int*   mask = (const int*)  d_in[3];
    const float* Wq   = (const float*)d_in[4];
    const float* Wk   = (const float*)d_in[5];
    const float* Wv   = (const float*)d_in[6];
    const float* Wo   = (const float*)d_in[7];
    float* out = (float*)d_out;

    unsigned short* ws  = (unsigned short*)d_ws;
    const size_t n1 = (size_t)NB * NH * SEQ * DHEAD;      // 4,194,304
    const size_t nw = (size_t)NH * DHEAD * DMODEL;        // 1,048,576
    unsigned short* qh  = ws;
    unsigned short* kh  = qh + n1;
    unsigned short* vt  = kh + n1;                        // [bh][dh][seq]
    unsigned short* att = vt + n1;
    unsigned short* Wqt = att + n1;
    unsigned short* Wkt = Wqt + nw;
    unsigned short* Wvt = Wkt + nw;
    unsigned short* Wot = Wvt + nw;
    unsigned long long* mpack = (unsigned long long*)(Wot + (size_t)DMODEL * DMODEL);

    pack_mask_kernel<<<dim3(NB * SEQ / 4), 256, 0, stream>>>(mask, mpack);
    transpose_qkv_kernel<<<dim3(16, 48), 256, 0, stream>>>(Wq, Wk, Wv, Wqt, Wkt, Wvt);
    transpose_wo_kernel<<<dim3(16, 16), 256, 0, stream>>>(Wo, Wot);

    proj_gemm_kernel<<<dim3(8, 32, 3), 256, 0, stream>>>(q, k, v, Wqt, Wkt, Wvt, qh, kh, vt);
    attn_kernel<<<dim3(SEQ / 64, NB * NH), 256, 0, stream>>>(qh, kh, vt, mpack, att);
    out_gemm_kernel<<<dim3(16, 32), 256, 0, stream>>>(att, Wot, out);
}

// Round 4
// 342.678 us; speedup vs baseline: 1.4244x; 1.4244x over previous
//
#include <hip/hip_runtime.h>

#define NB 2
#define NH 16
#define SEQ 2048
#define DMODEL 1024
#define DHEAD 64
// 0.125 (1/sqrt(DH)) / ln(2): folded into Wq so softmax is a bare exp2
#define QSCALE 0.18033688f

typedef __attribute__((ext_vector_type(8))) short bf16x8;
typedef __attribute__((ext_vector_type(4))) float f32x4;

static __device__ __forceinline__ unsigned short f2bf(float f) {
    unsigned int u = __float_as_uint(f);
    u += 0x7fffu + ((u >> 16) & 1u);   // RNE
    return (unsigned short)(u >> 16);
}
static __device__ __forceinline__ unsigned int pk2(float lo, float hi) {
    return (unsigned int)f2bf(lo) | ((unsigned int)f2bf(hi) << 16);
}
static __device__ __forceinline__ void gld_lds16(const unsigned short* g, unsigned short* l) {
    __builtin_amdgcn_global_load_lds(
        (const __attribute__((address_space(1))) unsigned int*)g,
        (__attribute__((address_space(3))) unsigned int*)l, 16, 0, 0);
}

// =====================================================================
// Prep A: pack bool mask (int32) into u64 bitmask words per (b,s) row.
// =====================================================================
__global__ __launch_bounds__(256) void pack_mask_kernel(
    const int* __restrict__ mask, unsigned long long* __restrict__ mpack)
{
    const int wave = blockIdx.x * 4 + (threadIdx.x >> 6);
    const int lane = threadIdx.x & 63;
    const int* row = mask + (size_t)wave * SEQ;
    unsigned long long* orow = mpack + (size_t)wave * (SEQ / 64);
    for (int w = 0; w < SEQ / 64; ++w) {
        int m = row[w * 64 + lane];
        unsigned long long bits = __ballot(m != 0);
        if (lane == 0) orow[w] = bits;
    }
}

// =====================================================================
// Prep B1: fused Wq/Wk/Wv transpose+cvt (per head 1024x64 -> 64x1024).
// Wq additionally scaled by QSCALE. grid (16, 48).
// =====================================================================
__global__ __launch_bounds__(256) void transpose_qkv_kernel(
    const float* __restrict__ Wq, const float* __restrict__ Wk, const float* __restrict__ Wv,
    unsigned short* __restrict__ Wqt, unsigned short* __restrict__ Wkt, unsigned short* __restrict__ Wvt)
{
    const int z = blockIdx.y, sel = z >> 4, h = z & 15;
    const float* S = (sel == 0 ? Wq : sel == 1 ? Wk : Wv) + (size_t)h * DMODEL * DHEAD;
    unsigned short* D = (sel == 0 ? Wqt : sel == 1 ? Wkt : Wvt) + (size_t)h * DMODEL * DHEAD;
    const float scale = (sel == 0) ? QSCALE : 1.0f;
    const int tile_r = blockIdx.x * 64;
    __shared__ float Ls[64][65];
    const int t = threadIdx.x;
    const int c4 = (t & 15) * 4;
    for (int rr = t >> 4; rr < 64; rr += 16) {
        float4 v = *(const float4*)(S + (size_t)(tile_r + rr) * DHEAD + c4);
        Ls[rr][c4 + 0] = v.x; Ls[rr][c4 + 1] = v.y;
        Ls[rr][c4 + 2] = v.z; Ls[rr][c4 + 3] = v.w;
    }
    __syncthreads();
    const int r4 = (t & 15) * 4;
    for (int cc = t >> 4; cc < 64; cc += 16) {
        ushort4 o;
        o.x = f2bf(Ls[r4 + 0][cc] * scale); o.y = f2bf(Ls[r4 + 1][cc] * scale);
        o.z = f2bf(Ls[r4 + 2][cc] * scale); o.w = f2bf(Ls[r4 + 3][cc] * scale);
        *(ushort4*)(D + (size_t)cc * DMODEL + tile_r + r4) = o;
    }
}

// =====================================================================
// Prep B2: Wo transpose+cvt (1024x1024). grid (16, 16).
// =====================================================================
__global__ __launch_bounds__(256) void transpose_wo_kernel(
    const float* __restrict__ src, unsigned short* __restrict__ dst)
{
    const int tile_c = blockIdx.x * 64, tile_r = blockIdx.y * 64;
    __shared__ float Ls[64][65];
    const int t = threadIdx.x;
    const int c4 = (t & 15) * 4;
    for (int rr = t >> 4; rr < 64; rr += 16) {
        float4 v = *(const float4*)(src + (size_t)(tile_r + rr) * DMODEL + tile_c + c4);
        Ls[rr][c4 + 0] = v.x; Ls[rr][c4 + 1] = v.y;
        Ls[rr][c4 + 2] = v.z; Ls[rr][c4 + 3] = v.w;
    }
    __syncthreads();
    const int r4 = (t & 15) * 4;
    for (int cc = t >> 4; cc < 64; cc += 16) {
        ushort4 o;
        o.x = f2bf(Ls[r4 + 0][cc]); o.y = f2bf(Ls[r4 + 1][cc]);
        o.z = f2bf(Ls[r4 + 2][cc]); o.w = f2bf(Ls[r4 + 3][cc]);
        *(ushort4*)(dst + (size_t)(tile_c + cc) * DMODEL + tile_r + r4) = o;
    }
}

// =====================================================================
// Fused projection GEMM: z in {0,1,2} selects (q,Wqt->qh),(k,Wkt->kh),
// (v,Wvt->vt transposed [bh][dh][seq]).  128x128 tile, BK=64, 4 waves.
// grid (8, 32, 3) = 768 blocks (3 blocks/CU).
// =====================================================================
__global__ __launch_bounds__(256) void proj_gemm_kernel(
    const float* __restrict__ q, const float* __restrict__ k, const float* __restrict__ v,
    const unsigned short* __restrict__ Wqt, const unsigned short* __restrict__ Wkt,
    const unsigned short* __restrict__ Wvt,
    unsigned short* __restrict__ qh, unsigned short* __restrict__ kh,
    unsigned short* __restrict__ vt)
{
    const int z = blockIdx.z;
    const float* A = (z == 0) ? q : (z == 1) ? k : v;
    const unsigned short* Bt = (z == 0) ? Wqt : (z == 1) ? Wkt : Wvt;

    const int t = threadIdx.x, lane = t & 63, w = t >> 6;
    const int lg = lane >> 4, ln = lane & 15;
    const int wx = w & 1, wy = w >> 1;
    const int m0 = blockIdx.y * 128, n0 = blockIdx.x * 128;

    __shared__ __align__(16) unsigned short As[128 * 64];
    __shared__ __align__(16) unsigned short Bs[128 * 64];

    f32x4 acc[4][4] = {};

    for (int kk = 0; kk < DMODEL; kk += 64) {
        #pragma unroll
        for (int i = 0; i < 4; ++i) {
            int s = (w * 4 + i) * 64 + lane;
            int n = s >> 3, c = (s & 7) ^ (n & 7);
            gld_lds16(Bt + (size_t)(n0 + n) * DMODEL + kk + c * 8, Bs + (size_t)s * 8);
        }
        {
            const int row = t >> 1, kh2 = (t & 1) * 32;
            const float* Ag = A + (size_t)(m0 + row) * DMODEL + kk + kh2;
            #pragma unroll
            for (int j = 0; j < 4; ++j) {
                float4 x0 = *(const float4*)(Ag + j * 8);
                float4 x1 = *(const float4*)(Ag + j * 8 + 4);
                uint4 val;
                val.x = pk2(x0.x, x0.y); val.y = pk2(x0.z, x0.w);
                val.z = pk2(x1.x, x1.y); val.w = pk2(x1.z, x1.w);
                int c = (kh2 >> 3) + j;
                *(uint4*)(As + row * 64 + ((c ^ (row & 7)) * 8)) = val;
            }
        }
        __syncthreads();
        #pragma unroll
        for (int ks = 0; ks < 2; ++ks) {
            bf16x8 af[4], bf[4];
            #pragma unroll
            for (int rb = 0; rb < 4; ++rb) {
                int r = wy * 64 + rb * 16 + ln;
                af[rb] = *(const bf16x8*)(As + r * 64 + (((ks * 4 + lg) ^ (r & 7)) * 8));
            }
            #pragma unroll
            for (int nb = 0; nb < 4; ++nb) {
                int n = wx * 64 + nb * 16 + ln;
                bf[nb] = *(const bf16x8*)(Bs + n * 64 + (((ks * 4 + lg) ^ (n & 7)) * 8));
            }
            #pragma unroll
            for (int rb = 0; rb < 4; ++rb)
                #pragma unroll
                for (int nb = 0; nb < 4; ++nb)
                    acc[rb][nb] = __builtin_amdgcn_mfma_f32_16x16x32_bf16(
                        af[rb], bf[nb], acc[rb][nb], 0, 0, 0);
        }
        __syncthreads();
    }

    if (z < 2) {
        unsigned short* Y = (z == 0) ? qh : kh;   // [bh][s][dh]
        #pragma unroll
        for (int rb = 0; rb < 4; ++rb)
            #pragma unroll
            for (int nb = 0; nb < 4; ++nb)
                #pragma unroll
                for (int r = 0; r < 4; ++r) {
                    int grow = m0 + wy * 64 + rb * 16 + lg * 4 + r;   // b*2048+s
                    int gcol = n0 + wx * 64 + nb * 16 + ln;           // h*64+e
                    size_t idx = ((size_t)((grow >> 11) * NH + (gcol >> 6)) * SEQ
                                  + (grow & (SEQ - 1))) * DHEAD + (gcol & 63);
                    Y[idx] = f2bf(acc[rb][nb][r]);
                }
    } else {
        // V transposed: vt[bh][dh][seq]
        #pragma unroll
        for (int rb = 0; rb < 4; ++rb)
            #pragma unroll
            for (int nb = 0; nb < 4; ++nb) {
                int grow0 = m0 + wy * 64 + rb * 16 + lg * 4;          // b*2048+s (s%4==0)
                int gcol  = n0 + wx * 64 + nb * 16 + ln;              // h*64+dh
                int bh = ((grow0 >> 11) << 4) + (gcol >> 6);
                ushort4 st;
                st.x = f2bf(acc[rb][nb][0]); st.y = f2bf(acc[rb][nb][1]);
                st.z = f2bf(acc[rb][nb][2]); st.w = f2bf(acc[rb][nb][3]);
                *(ushort4*)(vt + ((size_t)bh * DHEAD + (gcol & 63)) * SEQ
                                 + (grow0 & (SEQ - 1))) = st;
            }
    }
}

// =====================================================================
// MFMA flash attention, LDS-staged (m97-style). grid (32, 32), block 256.
// Wave w owns q-rows [row0+16w, +16). 128-key tiles, 16 iterations.
// K tile + V^T tile staged via global_load_lds (16B, XOR-swizzled source).
// exp2-only softmax (scale folded into Wq), deferred l-reduction,
// wave-private P round-trip (no barrier needed within the compute phase).
// =====================================================================
__global__ __launch_bounds__(256) void attn_kernel(
    const unsigned short* __restrict__ qh, const unsigned short* __restrict__ kh,
    const unsigned short* __restrict__ vt, const unsigned long long* __restrict__ mpack,
    unsigned short* __restrict__ att)
{
    const int t = threadIdx.x, lane = t & 63, w = t >> 6;
    const int lg = lane >> 4, ln = lane & 15;
    const int row0 = blockIdx.x * 64;
    const int bh = blockIdx.y, b = bh >> 4, h = bh & 15;

    __shared__ __align__(16) unsigned short Ks[128 * 64];    // [key][dh/8 swizzled]
    __shared__ __align__(16) unsigned short Vs[64 * 128];    // [dh][key/8 swizzled]
    __shared__ __align__(16) unsigned short Ps[4][16][136];  // wave-private P

    const unsigned short* Qb = qh + ((size_t)bh * SEQ + row0 + w * 16 + ln) * DHEAD;
    bf16x8 qf0 = *(const bf16x8*)(Qb + lg * 8);
    bf16x8 qf1 = *(const bf16x8*)(Qb + 32 + lg * 8);

    const unsigned short* Kb = kh + (size_t)bh * SEQ * DHEAD;
    const unsigned short* Vb = vt + (size_t)bh * DHEAD * SEQ;
    const unsigned long long* Mb = mpack + ((size_t)b * SEQ + row0 + w * 16) * (SEQ / 64);

    f32x4 O[4] = {};
    float lsum[4] = {0.f, 0.f, 0.f, 0.f};

    for (int kt = 0; kt < SEQ; kt += 128) {
        __syncthreads();   // previous iteration's LDS reads complete
        // ---- stage K tile: 128 keys x 64 dh (8 chunks of 8, src-swizzled) ----
        #pragma unroll
        for (int i = 0; i < 4; ++i) {
            int s = i * 256 + t;
            int n = s >> 3, c = (s & 7) ^ (n & 7);
            gld_lds16(Kb + (size_t)(kt + n) * DHEAD + c * 8, Ks + (size_t)s * 8);
        }
        // ---- stage V^T tile: 64 dh x 128 keys (16 chunks of 8, src-swizzled) ----
        #pragma unroll
        for (int i = 0; i < 4; ++i) {
            int s = i * 256 + t;
            int n = s >> 4, c = (s & 15) ^ (n & 7);
            gld_lds16(Vb + (size_t)n * SEQ + kt + c * 8, Vs + (size_t)s * 8);
        }
        __syncthreads();   // loads drained (vmcnt(0) before barrier)

        // ---- S = Q K^T  (8 key-blocks of 16) ----
        f32x4 S[8];
        #pragma unroll
        for (int kb = 0; kb < 8; ++kb) {
            int r = kb * 16 + ln;
            const unsigned short* kp = Ks + r * 64;
            bf16x8 k0 = *(const bf16x8*)(kp + ((lg       ^ (r & 7)) * 8));
            bf16x8 k1 = *(const bf16x8*)(kp + (((lg + 4) ^ (r & 7)) * 8));
            f32x4 z = {0.f, 0.f, 0.f, 0.f};
            z = __builtin_amdgcn_mfma_f32_16x16x32_bf16(qf0, k0, z, 0, 0, 0);
            S[kb] = __builtin_amdgcn_mfma_f32_16x16x32_bf16(qf1, k1, z, 0, 0, 0);
        }

        // ---- masked exp2, accumulate l, write P (wave-private) ----
        #pragma unroll
        for (int r = 0; r < 4; ++r) {
            const size_t mrow = (size_t)(lg * 4 + r) * (SEQ / 64) + (kt >> 6);
            unsigned long long mw0 = Mb[mrow];
            unsigned long long mw1 = Mb[mrow + 1];
            #pragma unroll
            for (int kb = 0; kb < 8; ++kb) {
                const unsigned long long mword = (kb < 4) ? mw0 : mw1;
                const bool m = (mword >> ((kb & 3) * 16 + ln)) & 1ull;
                float e = m ? 0.0f : exp2f(S[kb][r]);
                lsum[r] += e;
                Ps[w][lg * 4 + r][kb * 16 + ln] = f2bf(e);
            }
        }

        // ---- O += P @ V  (same-wave DS ordering; no barrier) ----
        #pragma unroll
        for (int ks = 0; ks < 4; ++ks) {
            bf16x8 af = *(const bf16x8*)(&Ps[w][ln][ks * 32 + lg * 8]);
            #pragma unroll
            for (int nb = 0; nb < 4; ++nb) {
                int r = nb * 16 + ln;
                int pos = (ks * 4 + lg) ^ (r & 7);
                bf16x8 bfr = *(const bf16x8*)(Vs + r * 128 + pos * 8);
                O[nb] = __builtin_amdgcn_mfma_f32_16x16x32_bf16(af, bfr, O[nb], 0, 0, 0);
            }
        }
    }

    // ---- epilogue: one l-reduction, normalize, head-concat store ----
    unsigned short* ob = att + ((size_t)b * SEQ + row0 + w * 16) * DMODEL + h * DHEAD;
    #pragma unroll
    for (int r = 0; r < 4; ++r) {
        float l = lsum[r];
        l += __shfl_xor(l, 1, 64);
        l += __shfl_xor(l, 2, 64);
        l += __shfl_xor(l, 4, 64);
        l += __shfl_xor(l, 8, 64);
        const float inv = 1.0f / l;
        #pragma unroll
        for (int nb = 0; nb < 4; ++nb)
            ob[(size_t)(lg * 4 + r) * DMODEL + nb * 16 + ln] = f2bf(O[nb][r] * inv);
    }
}

// =====================================================================
// Output GEMM: out[4096 x 1024] = att(bf16) @ Wot^T, f32 out.
// 128M x 64N tile, BK=64, 4 waves stacked in M. grid (16, 32) = 512 blocks.
// =====================================================================
__global__ __launch_bounds__(256) void out_gemm_kernel(
    const unsigned short* __restrict__ A, const unsigned short* __restrict__ Bt,
    float* __restrict__ C)
{
    const int t = threadIdx.x, lane = t & 63, w = t >> 6;
    const int lg = lane >> 4, ln = lane & 15;
    const int n0 = blockIdx.x * 64, m0 = blockIdx.y * 128;

    __shared__ __align__(16) unsigned short As[128 * 64];
    __shared__ __align__(16) unsigned short Bs[64 * 64];

    f32x4 acc[2][4] = {};

    for (int kk = 0; kk < DMODEL; kk += 64) {
        #pragma unroll
        for (int i = 0; i < 2; ++i) {
            int s = i * 256 + t;
            int n = s >> 3, c = (s & 7) ^ (n & 7);
            gld_lds16(Bt + (size_t)(n0 + n) * DMODEL + kk + c * 8, Bs + (size_t)s * 8);
        }
        #pragma unroll
        for (int i = 0; i < 4; ++i) {
            int s = i * 256 + t;
            int n = s >> 3, c = (s & 7) ^ (n & 7);
            gld_lds16(A + (size_t)(m0 + n) * DMODEL + kk + c * 8, As + (size_t)s * 8);
        }
        __syncthreads();
        #pragma unroll
        for (int ks = 0; ks < 2; ++ks) {
            bf16x8 af[2], bf[4];
            #pragma unroll
            for (int rb = 0; rb < 2; ++rb) {
                int r = w * 32 + rb * 16 + ln;
                af[rb] = *(const bf16x8*)(As + r * 64 + (((ks * 4 + lg) ^ (r & 7)) * 8));
            }
            #pragma unroll
            for (int nb = 0; nb < 4; ++nb) {
                int n = nb * 16 + ln;
                bf[nb] = *(const bf16x8*)(Bs + n * 64 + (((ks * 4 + lg) ^ (n & 7)) * 8));
            }
            #pragma unroll
            for (int rb = 0; rb < 2; ++rb)
                #pragma unroll
                for (int nb = 0; nb < 4; ++nb)
                    acc[rb][nb] = __builtin_amdgcn_mfma_f32_16x16x32_bf16(
                        af[rb], bf[nb], acc[rb][nb], 0, 0, 0);
        }
        __syncthreads();
    }

    #pragma unroll
    for (int rb = 0; rb < 2; ++rb)
        #pragma unroll
        for (int nb = 0; nb < 4; ++nb)
            #pragma unroll
            for (int r = 0; r < 4; ++r) {
                int grow = m0 + w * 32 + rb * 16 + lg * 4 + r;
                int gcol = n0 + nb * 16 + ln;
                C[(size_t)grow * DMODEL + gcol] = acc[rb][nb][r];
            }
}

extern "C" void kernel_launch(void* const* d_in, const int* in_sizes, int n_in,
                              void* d_out, int out_size, void* d_ws, size_t ws_size,
                              hipStream_t stream) {
    const float* q    = (const float*)d_in[0];
    const float* k    = (const float*)d_in[1];
    const float* v    = (const float*)d_in[2];
    const int*   mask = (const int*)  d_in[3];
    const float* Wq   = (const float*)d_in[4];
    const float* Wk   = (const float*)d_in[5];
    const float* Wv   = (const float*)d_in[6];
    const float* Wo   = (const float*)d_in[7];
    float* out = (float*)d_out;

    unsigned short* ws  = (unsigned short*)d_ws;
    const size_t n1 = (size_t)NB * NH * SEQ * DHEAD;      // 4,194,304
    const size_t nw = (size_t)NH * DHEAD * DMODEL;        // 1,048,576
    unsigned short* qh  = ws;
    unsigned short* kh  = qh + n1;
    unsigned short* vt  = kh + n1;                        // [bh][dh][seq]
    unsigned short* att = vt + n1;
    unsigned short* Wqt = att + n1;
    unsigned short* Wkt = Wqt + nw;
    unsigned short* Wvt = Wkt + nw;
    unsigned short* Wot = Wvt + nw;
    unsigned long long* mpack = (unsigned long long*)(Wot + (size_t)DMODEL * DMODEL);

    pack_mask_kernel<<<dim3(NB * SEQ / 4), 256, 0, stream>>>(mask, mpack);
    transpose_qkv_kernel<<<dim3(16, 48), 256, 0, stream>>>(Wq, Wk, Wv, Wqt, Wkt, Wvt);
    transpose_wo_kernel<<<dim3(16, 16), 256, 0, stream>>>(Wo, Wot);

    proj_gemm_kernel<<<dim3(8, 32, 3), 256, 0, stream>>>(q, k, v, Wqt, Wkt, Wvt, qh, kh, vt);
    attn_kernel<<<dim3(SEQ / 64, NB * NH), 256, 0, stream>>>(qh, kh, vt, mpack, att);
    out_gemm_kernel<<<dim3(16, 32), 256, 0, stream>>>(att, Wot, out);
}